// Round 11
// baseline (128.855 us; speedup 1.0000x reference)
//
#include <hip/hip_runtime.h>
#include <hip/hip_fp16.h>
#include <math.h>

#define IMG_H 96
#define IMG_W 96
#define HW (IMG_H * IMG_W)
#define TW 16          // output w-tile per block
#define TH 4           // output h-rows per block (split across waves)
#define TR (TH + 4)    // staged rows (halo 2 top + 2 bottom)
#define TC 20          // tile cols = TW + 4 halo
#define TS2 36         // half2 stride per x-column: 32 chan-pairs + 4 pad (2-way = free)

// ws layout (floats): [0..399] wpk half2-bits, [400..911] msh, [912..1423] ash
#define WS_MSH 400
#define WS_ASH 912

// quad (lanes tid&3) butterfly reductions via DPP quad_perm
__device__ __forceinline__ float quad_sum(float v) {
    v += __int_as_float(__builtin_amdgcn_update_dpp(
            0, __float_as_int(v), 0xB1, 0xF, 0xF, true));   // quad_perm [1,0,3,2]
    v += __int_as_float(__builtin_amdgcn_update_dpp(
            0, __float_as_int(v), 0x4E, 0xF, 0xF, true));   // quad_perm [2,3,0,1]
    return v;
}
__device__ __forceinline__ float quad_max(float v) {
    v = fmaxf(v, __int_as_float(__builtin_amdgcn_update_dpp(
            0, __float_as_int(v), 0xB1, 0xF, 0xF, true)));
    v = fmaxf(v, __int_as_float(__builtin_amdgcn_update_dpp(
            0, __float_as_int(v), 0x4E, 0xF, 0xF, true)));
    return v;
}

// 3-iter dynamic routing; quad lane q owns z rows: pos z = q*4+0..3,
// app z = 16+q*4+0..3. p_z lane-local; mx/n2/dp/da via quad butterflies.
__device__ __forceinline__ void route_store(const float (*uh)[8], int q, int nt,
                                            int pix, float* __restrict__ out)
{
    float bb[4] = {0.0f, 0.0f, 0.0f, 0.0f};
    #pragma unroll
    for (int it = 0; it < 2; ++it) {
        float r0 = 1.0f / (1.0f + __expf(-bb[0]));
        float r1 = 1.0f / (1.0f + __expf(-bb[1]));
        float r2 = 1.0f / (1.0f + __expf(-bb[2]));
        float r3 = 1.0f / (1.0f + __expf(-bb[3]));
        float pz[4], pa[4];
        #pragma unroll
        for (int j = 0; j < 4; ++j)
            pz[j] = fmaf(uh[0][j], r0, fmaf(uh[1][j], r1,
                    fmaf(uh[2][j], r2, uh[3][j] * r3)));
        float mx = quad_max(fmaxf(fmaxf(fabsf(pz[0]), fabsf(pz[1])),
                                  fmaxf(fabsf(pz[2]), fabsf(pz[3]))));
        float dp[4];
        #pragma unroll
        for (int o = 0; o < 4; ++o)
            dp[o] = quad_sum(fmaf(uh[o][0], pz[0], fmaf(uh[o][1], pz[1],
                             fmaf(uh[o][2], pz[2], uh[o][3] * pz[3]))));
        #pragma unroll
        for (int j = 0; j < 4; ++j)
            pa[j] = fmaf(uh[0][4 + j], r0, fmaf(uh[1][4 + j], r1,
                    fmaf(uh[2][4 + j], r2, uh[3][4 + j] * r3)));
        float n2 = quad_sum(fmaf(pa[0], pa[0], fmaf(pa[1], pa[1],
                            fmaf(pa[2], pa[2], pa[3] * pa[3]))));
        float invm = 1.0f / mx;                               // psquash
        float sc   = n2 / ((1.0f + n2) * sqrtf(n2 + 1e-9f));  // matwo squash
        #pragma unroll
        for (int o = 0; o < 4; ++o) {
            float da = quad_sum(fmaf(uh[o][4], pa[0], fmaf(uh[o][5], pa[1],
                               fmaf(uh[o][6], pa[2], uh[o][7] * pa[3]))));
            bb[o] += (invm * dp[o]) * (sc * da);
        }
    }
    float r0 = 1.0f / (1.0f + __expf(-bb[0]));
    float r1 = 1.0f / (1.0f + __expf(-bb[1]));
    float r2 = 1.0f / (1.0f + __expf(-bb[2]));
    float r3 = 1.0f / (1.0f + __expf(-bb[3]));
    float pz[4], pa[4];
    #pragma unroll
    for (int j = 0; j < 4; ++j)
        pz[j] = fmaf(uh[0][j], r0, fmaf(uh[1][j], r1,
                fmaf(uh[2][j], r2, uh[3][j] * r3)));
    float mx = quad_max(fmaxf(fmaxf(fabsf(pz[0]), fabsf(pz[1])),
                              fmaxf(fabsf(pz[2]), fabsf(pz[3]))));
    #pragma unroll
    for (int j = 0; j < 4; ++j)
        pa[j] = fmaf(uh[0][4 + j], r0, fmaf(uh[1][4 + j], r1,
                fmaf(uh[2][4 + j], r2, uh[3][4 + j] * r3)));
    float n2 = quad_sum(fmaf(pa[0], pa[0], fmaf(pa[1], pa[1],
                        fmaf(pa[2], pa[2], pa[3] * pa[3]))));
    float invm = 1.0f / mx;
    float sc   = n2 / ((1.0f + n2) * sqrtf(n2 + 1e-9f));
    // unmasked stores: lane q owns z = q*4+j (pos) and 16+q*4+j (app)
    float* op = out + ((size_t)nt * 32 + (q << 2)) * HW + pix;
    op[0 * HW] = pz[0] * invm;
    op[1 * HW] = pz[1] * invm;
    op[2 * HW] = pz[2] * invm;
    op[3 * HW] = pz[3] * invm;
    op[16 * HW] = pa[0] * sc;
    op[17 * HW] = pa[1] * sc;
    op[18 * HW] = pa[2] * sc;
    op[19 * HW] = pa[3] * sc;
}

// one-block pre-pack: conv weights (o-paired half2) + normalized W_pos + raw W_app
__global__ void __launch_bounds__(256)
caps_pack_kernel(const float* __restrict__ Wc, const float* __restrict__ Wp,
                 const float* __restrict__ Wa, float* __restrict__ ws)
{
    const int tid = threadIdx.x;
    for (int i = tid; i < 400; i += 256) {
        int fp  = i / 100;
        int rem = i - fp * 100;
        int tap = rem >> 2;
        int g   = i & 3;
        int oe  = (g & 1) << 1;                // 0 or 2
        int f   = fp + ((g >> 1) << 2);        // pos: fp, app: fp+4
        __half2 hv = __floats2half2_rn(Wc[oe * 200 + tap * 8 + f],
                                       Wc[(oe + 1) * 200 + tap * 8 + f]);
        ((__half2*)ws)[i] = hv;
    }
    if (tid < 128) {
        int c  = tid & 3;                      // p1 column
        int tt = (tid >> 2) & 7;
        int oo = tid >> 5;
        const float* src = Wp + oo * 128 + tt * 16 + c;
        float v0 = src[0], v1 = src[4], v2 = src[8], v3 = src[12];
        float s = v0 * v0 + v1 * v1 + v2 * v2 + v3 * v3;
        float inv = 1.0f / sqrtf(fmaxf(s, 1e-12f));
        float* dst = ws + WS_MSH + (oo * 8 + tt) * 16 + c;
        dst[0] = v0 * inv; dst[4] = v1 * inv; dst[8] = v2 * inv; dst[12] = v3 * inv;
    } else {
        int i = tid - 128;
        ((float4*)(ws + WS_ASH))[i] = ((const float4*)Wa)[i];
    }
}

// Block 1024 = 4 q (lane&3) x 16 px x 16 waves; wave wv handles
// capsule t = parity + 2*(wv&3) and output row rr = wv>>2 (0..3).
// Grid (6, 24, n*2+parity). Weights/matrices via s_load (scalar cache);
// LDS holds ONLY the input tile. Conv A/B ROW DOUBLE-BUFFERED in VGPRs:
// row dy+1's 10 ds_read_b128 issue while row dy's 80 hfma2 execute
// (160 VALU cyc covers ~120 LDS cyc -> per-wave latency self-hidden).
// __launch_bounds__(1024, 4): VGPR cap 128 (buffer needs ~108).
__global__ void __launch_bounds__(1024, 4)
caps_one_kernel(const float* __restrict__ x,    // (4,4,32,96,96)
                const float* __restrict__ ws,   // packed weights (see layout)
                const float* __restrict__ Ba,   // (4,8)
                float* __restrict__ out)        // (4,8,32,96,96)
{
    __shared__ __align__(16) __half2 tile2[TR * TC * TS2];  // 23.0 KB

    const int tid    = threadIdx.x;
    const int q      = tid & 3;                // z-row quad lane
    const int px     = (tid >> 2) & 15;
    const int wv     = tid >> 6;               // wave 0..15
    const int wb     = blockIdx.x * TW;
    const int h0     = blockIdx.y * TH;
    const int n      = blockIdx.z >> 1;
    const int parity = blockIdx.z & 1;
    // wave-uniform scalars (force SGPR so weight reads become s_load)
    const int t      = __builtin_amdgcn_readfirstlane(parity + 2 * (wv & 3));
    const int rr     = __builtin_amdgcn_readfirstlane(wv >> 2);
    const int w      = wb + px;
    const int h      = h0 + rr;

    // ---- staging: interior, EXACT one b128 unit per thread ----
    {
        const int col = tid & 15;
        const int g   = tid >> 4;              // 0..63 = dy*8 + cpg exact
        const int dy    = g >> 3;              // 0..7
        const int cpg   = g & 7;
        const int hh    = h0 + dy - 2;
        const int zq    = cpg >> 1;
        const int cbase = (cpg & 1) << 1;
        const int chan  = n * 128 + parity * 16 + zq * 4 + cbase;  // o=0 comp
        float v[8];
        #pragma unroll
        for (int j = 0; j < 8; ++j) v[j] = 0.0f;
        if ((unsigned)hh < IMG_H) {
            const float* src = x + (size_t)chan * HW + hh * IMG_W + wb + col;
            #pragma unroll
            for (int j = 0; j < 8; ++j)           // o = j&3, c = cbase+(j>>2)
                v[j] = src[(size_t)((j & 3) * 32 + (j >> 2)) * HW];
        }
        __half2 h4[4];
        #pragma unroll
        for (int j = 0; j < 4; ++j)               // pairs (o even, o odd)
            h4[j] = __floats2half2_rn(v[2 * j], v[2 * j + 1]);
        *(uint4*)&tile2[(dy * TC + 2 + col) * TS2 + (cpg << 2)] =
            *(const uint4*)h4;

        // halo: x in {0,1,18,19}, EXACT one half2 unit per thread
        const int m  = tid & 3;
        const int xx = (m < 2) ? m : (m + TW);
        const int ww = wb - 2 + xx;
        const int rh = tid >> 2;               // 0..255 = dy*32 + cp exact
        const int hdy = rh >> 5;               // 0..7
        const int cp  = rh & 31;
        const int hhh = h0 + hdy - 2;
        const int o0  = (cp & 1) << 1;
        const int hc  = (cp >> 1) & 3;
        const int hzq = cp >> 3;
        const int hchan = n * 128 + o0 * 32 + parity * 16 + hzq * 4 + hc;
        float v0 = 0.0f, v1 = 0.0f;
        if ((unsigned)hhh < IMG_H && (unsigned)ww < IMG_W) {
            const float* src = x + (size_t)hchan * HW + hhh * IMG_W + ww;
            v0 = src[0];
            v1 = src[(size_t)32 * HW];
        }
        tile2[(hdy * TC + xx) * TS2 + cp] = __floats2half2_rn(v0, v1);
    }
    __syncthreads();

    // ---- conv 5x5: row double-buffered A/B, weights via s_load ----
    __half2 rp2[8], ra2[8];
    const __half2 z2 = __float2half2_rn(0.0f);
    #pragma unroll
    for (int i = 0; i < 8; ++i) { rp2[i] = z2; ra2[i] = z2; }

    const uint4* wq = (const uint4*)ws + (t >> 1) * 25;   // 25 taps x 16B, SGPR

    uint4 a0[5], b0[5], a1[5], b1[5];
    #pragma unroll
    for (int dx = 0; dx < 5; ++dx) {
        const __half2* t2 = &tile2[(rr * TC + px + dx) * TS2 + (q << 3)];
        a0[dx] = *(const uint4*)t2;
        b0[dx] = *(const uint4*)(t2 + 4);
    }
    #pragma unroll
    for (int dy = 0; dy < 5; ++dy) {
        // prefetch next row into alternate buffer (static index per unrolled dy)
        if (dy < 4) {
            #pragma unroll
            for (int dx = 0; dx < 5; ++dx) {
                const __half2* t2 =
                    &tile2[((rr + dy + 1) * TC + px + dx) * TS2 + (q << 3)];
                if ((dy & 1) == 0) {
                    a1[dx] = *(const uint4*)t2; b1[dx] = *(const uint4*)(t2 + 4);
                } else {
                    a0[dx] = *(const uint4*)t2; b0[dx] = *(const uint4*)(t2 + 4);
                }
            }
        }
        // compute on current row
        #pragma unroll
        for (int dx = 0; dx < 5; ++dx) {
            union { uint4 u; __half2 hh[4]; } A, B, Wt;
            A.u  = (dy & 1) ? a1[dx] : a0[dx];
            B.u  = (dy & 1) ? b1[dx] : b0[dx];
            Wt.u = wq[dy * 5 + dx];            // scalar-cache broadcast
            rp2[0] = __hfma2(A.hh[0], Wt.hh[0], rp2[0]);  // c0 o01 pos
            rp2[1] = __hfma2(A.hh[1], Wt.hh[1], rp2[1]);  // c0 o23 pos
            rp2[2] = __hfma2(A.hh[2], Wt.hh[0], rp2[2]);  // c1 o01
            rp2[3] = __hfma2(A.hh[3], Wt.hh[1], rp2[3]);  // c1 o23
            rp2[4] = __hfma2(B.hh[0], Wt.hh[0], rp2[4]);  // c2 o01
            rp2[5] = __hfma2(B.hh[1], Wt.hh[1], rp2[5]);  // c2 o23
            rp2[6] = __hfma2(B.hh[2], Wt.hh[0], rp2[6]);  // c3 o01
            rp2[7] = __hfma2(B.hh[3], Wt.hh[1], rp2[7]);  // c3 o23
            ra2[0] = __hfma2(A.hh[0], Wt.hh[2], ra2[0]);  // app
            ra2[1] = __hfma2(A.hh[1], Wt.hh[3], ra2[1]);
            ra2[2] = __hfma2(A.hh[2], Wt.hh[2], ra2[2]);
            ra2[3] = __hfma2(A.hh[3], Wt.hh[3], ra2[3]);
            ra2[4] = __hfma2(B.hh[0], Wt.hh[2], ra2[4]);
            ra2[5] = __hfma2(B.hh[1], Wt.hh[3], ra2[5]);
            ra2[6] = __hfma2(B.hh[2], Wt.hh[2], ra2[6]);
            ra2[7] = __hfma2(B.hh[3], Wt.hh[3], ra2[7]);
        }
    }

    // ---- emit u_hat[o][8]: matrices via s_load (wave-uniform) ----
    float uh[4][8];
    {
        const float cx = (float)w * (1.0f / 96.0f);
        const float cy = (float)h * (1.0f / 96.0f);
        #pragma unroll
        for (int o = 0; o < 4; ++o) {
            const float* mb = ws + WS_MSH + (o * 8 + t) * 16;  // uniform addr
            float4 m0 = *(const float4*)(mb + 0);
            float4 m1 = *(const float4*)(mb + 4);
            float4 m2 = *(const float4*)(mb + 8);
            float4 m3 = *(const float4*)(mb + 12);
            m3.x += cx;                         // coord add [row3,col0]
            m3.y += cy;                         // [row3,col1]
            const int pr = o >> 1;
            float r0, r1, r2, r3;
            if (o & 1) {
                r0 = __high2float(rp2[0 + pr]); r1 = __high2float(rp2[2 + pr]);
                r2 = __high2float(rp2[4 + pr]); r3 = __high2float(rp2[6 + pr]);
            } else {
                r0 = __low2float(rp2[0 + pr]);  r1 = __low2float(rp2[2 + pr]);
                r2 = __low2float(rp2[4 + pr]);  r3 = __low2float(rp2[6 + pr]);
            }
            uh[o][0] = r0 * m0.x + r1 * m1.x + r2 * m2.x + r3 * m3.x;
            uh[o][1] = r0 * m0.y + r1 * m1.y + r2 * m2.y + r3 * m3.y;
            uh[o][2] = r0 * m0.z + r1 * m1.z + r2 * m2.z + r3 * m3.z;
            uh[o][3] = r0 * m0.w + r1 * m1.w + r2 * m2.w + r3 * m3.w;
        }
        #pragma unroll
        for (int o = 0; o < 4; ++o) {
            const float* ab = ws + WS_ASH + (o * 8 + t) * 16;  // uniform addr
            float4 a0_ = *(const float4*)(ab + 0);
            float4 a1_ = *(const float4*)(ab + 4);
            float4 a2_ = *(const float4*)(ab + 8);
            float4 a3_ = *(const float4*)(ab + 12);
            const float bias = Ba[o * 8 + t];
            const int pr = o >> 1;
            float r0, r1, r2, r3;
            if (o & 1) {
                r0 = __high2float(ra2[0 + pr]); r1 = __high2float(ra2[2 + pr]);
                r2 = __high2float(ra2[4 + pr]); r3 = __high2float(ra2[6 + pr]);
            } else {
                r0 = __low2float(ra2[0 + pr]);  r1 = __low2float(ra2[2 + pr]);
                r2 = __low2float(ra2[4 + pr]);  r3 = __low2float(ra2[6 + pr]);
            }
            r0 += bias; r1 += bias; r2 += bias; r3 += bias;
            uh[o][4] = r0 * a0_.x + r1 * a1_.x + r2 * a2_.x + r3 * a3_.x;
            uh[o][5] = r0 * a0_.y + r1 * a1_.y + r2 * a2_.y + r3 * a3_.y;
            uh[o][6] = r0 * a0_.z + r1 * a1_.z + r2 * a2_.z + r3 * a3_.z;
            uh[o][7] = r0 * a0_.w + r1 * a1_.w + r2 * a2_.w + r3 * a3_.w;
        }
    }

    route_store(uh, q, n * 8 + t, h * IMG_W + w, out);
}

extern "C" void kernel_launch(void* const* d_in, const int* in_sizes, int n_in,
                              void* d_out, int out_size, void* d_ws, size_t ws_size,
                              hipStream_t stream) {
    const float* x  = (const float*)d_in[0];
    const float* Wc = (const float*)d_in[1];
    const float* Wp = (const float*)d_in[2];
    const float* Wa = (const float*)d_in[3];
    const float* Ba = (const float*)d_in[4];
    float* outp = (float*)d_out;
    float* ws   = (float*)d_ws;

    caps_pack_kernel<<<dim3(1), 256, 0, stream>>>(Wc, Wp, Wa, ws);
    caps_one_kernel<<<dim3(IMG_W / TW, IMG_H / TH, 8), 1024, 0, stream>>>(
        x, ws, Ba, outp);
}

// Round 13
// 126.791 us; speedup vs baseline: 1.0163x; 1.0163x over previous
//
#include <hip/hip_runtime.h>
#include <hip/hip_fp16.h>
#include <math.h>

#define IMG_H 96
#define IMG_W 96
#define HW (IMG_H * IMG_W)
#define TW 16          // output w-tile per block
#define TH 4           // output h-rows per block (split across waves)
#define TR (TH + 4)    // staged rows (halo 2 top + 2 bottom)
#define TC 20          // tile cols = TW + 4 halo
#define TS2 36         // half2 stride per x-column: 32 chan-pairs + 4 pad (2-way = free)

typedef _Float16 hvec2 __attribute__((ext_vector_type(2)));
__device__ __forceinline__ float fdot2h(__half2 a, __half2 b, float c) {
    union { __half2 h; hvec2 v; } ua, ub;
    ua.h = a; ub.h = b;
    return __builtin_amdgcn_fdot2(ua.v, ub.v, c, false);
}

// quad (lanes tid&3) butterfly reductions via DPP quad_perm
__device__ __forceinline__ float quad_sum(float v) {
    v += __int_as_float(__builtin_amdgcn_update_dpp(
            0, __float_as_int(v), 0xB1, 0xF, 0xF, true));   // quad_perm [1,0,3,2]
    v += __int_as_float(__builtin_amdgcn_update_dpp(
            0, __float_as_int(v), 0x4E, 0xF, 0xF, true));   // quad_perm [2,3,0,1]
    return v;
}
__device__ __forceinline__ float quad_max(float v) {
    v = fmaxf(v, __int_as_float(__builtin_amdgcn_update_dpp(
            0, __float_as_int(v), 0xB1, 0xF, 0xF, true)));
    v = fmaxf(v, __int_as_float(__builtin_amdgcn_update_dpp(
            0, __float_as_int(v), 0x4E, 0xF, 0xF, true)));
    return v;
}

// 3-iter dynamic routing; quad lane q owns z rows: pos z = q*4+0..3,
// app z = 16+q*4+0..3. p_z lane-local; mx/n2/dp/da via quad butterflies.
__device__ __forceinline__ void route_store(const float (*uh)[8], int q, int nt,
                                            int pix, float* __restrict__ out)
{
    float bb[4] = {0.0f, 0.0f, 0.0f, 0.0f};
    #pragma unroll
    for (int it = 0; it < 2; ++it) {
        float r0 = 1.0f / (1.0f + __expf(-bb[0]));
        float r1 = 1.0f / (1.0f + __expf(-bb[1]));
        float r2 = 1.0f / (1.0f + __expf(-bb[2]));
        float r3 = 1.0f / (1.0f + __expf(-bb[3]));
        float pz[4], pa[4];
        #pragma unroll
        for (int j = 0; j < 4; ++j)
            pz[j] = fmaf(uh[0][j], r0, fmaf(uh[1][j], r1,
                    fmaf(uh[2][j], r2, uh[3][j] * r3)));
        float mx = quad_max(fmaxf(fmaxf(fabsf(pz[0]), fabsf(pz[1])),
                                  fmaxf(fabsf(pz[2]), fabsf(pz[3]))));
        float dp[4];
        #pragma unroll
        for (int o = 0; o < 4; ++o)
            dp[o] = quad_sum(fmaf(uh[o][0], pz[0], fmaf(uh[o][1], pz[1],
                             fmaf(uh[o][2], pz[2], uh[o][3] * pz[3]))));
        #pragma unroll
        for (int j = 0; j < 4; ++j)
            pa[j] = fmaf(uh[0][4 + j], r0, fmaf(uh[1][4 + j], r1,
                    fmaf(uh[2][4 + j], r2, uh[3][4 + j] * r3)));
        float n2 = quad_sum(fmaf(pa[0], pa[0], fmaf(pa[1], pa[1],
                            fmaf(pa[2], pa[2], pa[3] * pa[3]))));
        float invm = 1.0f / mx;                               // psquash
        float sc   = n2 / ((1.0f + n2) * sqrtf(n2 + 1e-9f));  // matwo squash
        #pragma unroll
        for (int o = 0; o < 4; ++o) {
            float da = quad_sum(fmaf(uh[o][4], pa[0], fmaf(uh[o][5], pa[1],
                               fmaf(uh[o][6], pa[2], uh[o][7] * pa[3]))));
            bb[o] += (invm * dp[o]) * (sc * da);
        }
    }
    float r0 = 1.0f / (1.0f + __expf(-bb[0]));
    float r1 = 1.0f / (1.0f + __expf(-bb[1]));
    float r2 = 1.0f / (1.0f + __expf(-bb[2]));
    float r3 = 1.0f / (1.0f + __expf(-bb[3]));
    float pz[4], pa[4];
    #pragma unroll
    for (int j = 0; j < 4; ++j)
        pz[j] = fmaf(uh[0][j], r0, fmaf(uh[1][j], r1,
                fmaf(uh[2][j], r2, uh[3][j] * r3)));
    float mx = quad_max(fmaxf(fmaxf(fabsf(pz[0]), fabsf(pz[1])),
                              fmaxf(fabsf(pz[2]), fabsf(pz[3]))));
    #pragma unroll
    for (int j = 0; j < 4; ++j)
        pa[j] = fmaf(uh[0][4 + j], r0, fmaf(uh[1][4 + j], r1,
                fmaf(uh[2][4 + j], r2, uh[3][4 + j] * r3)));
    float n2 = quad_sum(fmaf(pa[0], pa[0], fmaf(pa[1], pa[1],
                        fmaf(pa[2], pa[2], pa[3] * pa[3]))));
    float invm = 1.0f / mx;
    float sc   = n2 / ((1.0f + n2) * sqrtf(n2 + 1e-9f));
    // unmasked stores: lane q owns z = q*4+j (pos) and 16+q*4+j (app)
    float* op = out + ((size_t)nt * 32 + (q << 2)) * HW + pix;
    op[0 * HW] = pz[0] * invm;
    op[1 * HW] = pz[1] * invm;
    op[2 * HW] = pz[2] * invm;
    op[3 * HW] = pz[3] * invm;
    op[16 * HW] = pa[0] * sc;
    op[17 * HW] = pa[1] * sc;
    op[18 * HW] = pa[2] * sc;
    op[19 * HW] = pa[3] * sc;
}

// Block 1024 = 4 q (lane&3) x 16 px x 16 waves; wave wv handles
// capsule t = parity + 2*(wv&3) and output row rr = wv>>2 (0..3).
// Grid (6, 24, n*2+parity); block stages an 8-row tile serving 4 output rows.
// LDS channel order s = zq*16 + o*4 + c  (half2 = c-PAIRS within an o):
// conv accumulators come out (p1,p1+1)-paired so emit uses v_dot2_f32_f16
// (2 dot2 replace 4 fma + 4 cvt per output element). Matrices fp16; coord
// and bias contributions folded as fp32 fmas (bias via precomputed colsum).
__global__ void __launch_bounds__(1024, 8)
caps_one_kernel(const float* __restrict__ x,    // (4,4,32,96,96)
                const float* __restrict__ Wc,   // (4,5,5,1,8)
                const float* __restrict__ Wp,   // (4,16,8)
                const float* __restrict__ Wa,   // (4,16,8)
                const float* __restrict__ Ba,   // (4,8)
                float* __restrict__ out)        // (4,8,32,96,96)
{
    __shared__ __align__(16) __half2 tile2[TR * TC * TS2];  // 23.0 KB
    __shared__ __align__(16) __half2 wpk2[800];   // [s][tap][path][o] dup'd weights
    __shared__ __align__(16) __half2 mposh[256];  // [(o*8+t)][pair*4+col] norm pos
    __shared__ __align__(16) __half2 mapph[256];  // [(o*8+t)][pair*4+col] raw app
    __shared__ __align__(16) float   acs[512];    // [(o*8+t)*4+col] app colsums

    const int tid    = threadIdx.x;
    const int q      = tid & 3;                // z-row quad lane
    const int px     = (tid >> 2) & 15;
    const int wv     = tid >> 6;               // wave 0..15
    const int rr     = wv >> 2;                // output row within tile (0..3)
    const int wb     = blockIdx.x * TW;
    const int h0     = blockIdx.y * TH;
    const int n      = blockIdx.z >> 1;
    const int parity = blockIdx.z & 1;
    const int t      = parity + 2 * (wv & 3);  // capsule type for this wave
    const int w      = wb + px;
    const int h      = h0 + rr;

    // ---- precompute: conv weights, per-o DUPLICATED half2 ----
    if (tid < 800) {
        int s    = tid / 200;                  // f-pair slot 0..3
        int rem  = tid - s * 200;
        int tap  = rem >> 3;                   // 0..24
        int r2   = rem & 7;
        int path = r2 >> 2;                    // 0 pos, 1 app
        int o    = r2 & 3;
        float wvv = Wc[o * 200 + tap * 8 + path * 4 + s];
        wpk2[((s * 25 + tap) * 2 + path) * 4 + o] = __float2half2_rn(wvv);
    }
    // ---- precompute: normalized pos matrices as fp16 p1-pairs ----
    if (tid >= 768 && tid < 896) {
        int j  = tid - 768;
        int c  = j & 3;                        // column
        int tt = (j >> 2) & 7;
        int oo = j >> 5;
        const float* src = Wp + oo * 128 + tt * 16 + c;
        float v0 = src[0], v1 = src[4], v2 = src[8], v3 = src[12];
        float s = v0 * v0 + v1 * v1 + v2 * v2 + v3 * v3;
        float inv = 1.0f / sqrtf(fmaxf(s, 1e-12f));
        mposh[(oo * 8 + tt) * 8 + 0 + c] = __floats2half2_rn(v0 * inv, v1 * inv);
        mposh[(oo * 8 + tt) * 8 + 4 + c] = __floats2half2_rn(v2 * inv, v3 * inv);
    }
    // ---- precompute: app matrices fp16 p1-pairs + fp32 colsums ----
    if (tid >= 896) {
        int j  = tid - 896;
        int c  = j & 3;
        int tt = (j >> 2) & 7;
        int oo = j >> 5;
        const float* src = Wa + oo * 128 + tt * 16 + c;
        float a0 = src[0], a1 = src[4], a2 = src[8], a3 = src[12];
        mapph[(oo * 8 + tt) * 8 + 0 + c] = __floats2half2_rn(a0, a1);
        mapph[(oo * 8 + tt) * 8 + 4 + c] = __floats2half2_rn(a2, a3);
        acs[(oo * 8 + tt) * 4 + c] = a0 + a1 + a2 + a3;
    }
    // ---- staging: interior, EXACT one b128 unit per thread ----
    // half index s = zq*16 + o*4 + c; unit (dy,cpg) covers o={2(cpg&1),+1}, c0..3
    {
        const int col = tid & 15;
        const int g   = tid >> 4;              // 0..63 = dy*8 + cpg exact
        const int dy    = g >> 3;              // 0..7
        const int cpg   = g & 7;
        const int hh    = h0 + dy - 2;
        const int chan0 = n * 128 + ((cpg & 1) << 1) * 32 + parity * 16
                          + (cpg >> 1) * 4;    // o-base, c=0
        float v[8];
        #pragma unroll
        for (int j = 0; j < 8; ++j) v[j] = 0.0f;
        if ((unsigned)hh < IMG_H) {
            const float* src = x + (size_t)chan0 * HW + hh * IMG_W + wb + col;
            #pragma unroll
            for (int j = 0; j < 8; ++j)        // o_local = j>>2, c = j&3
                v[j] = src[(size_t)((j >> 2) * 32 + (j & 3)) * HW];
        }
        __half2 h4[4];
        #pragma unroll
        for (int j = 0; j < 4; ++j)            // pairs (c even, c odd)
            h4[j] = __floats2half2_rn(v[2 * j], v[2 * j + 1]);
        *(uint4*)&tile2[(dy * TC + 2 + col) * TS2 + (cpg << 2)] =
            *(const uint4*)h4;

        // halo: x in {0,1,18,19}, one half2 (c,c+1 adjacent chans) per thread
        const int m  = tid & 3;
        const int xx = (m < 2) ? m : (m + TW);
        const int ww = wb - 2 + xx;
        const int rh = tid >> 2;               // 0..255 = dy*32 + cp exact
        const int hdy = rh >> 5;               // 0..7
        const int cp  = rh & 31;
        const int hhh = h0 + hdy - 2;
        const int ho  = (cp >> 1) & 3;
        const int hzq = cp >> 3;
        const int hc  = (cp & 1) << 1;
        const int hchan = n * 128 + ho * 32 + parity * 16 + hzq * 4 + hc;
        float v0 = 0.0f, v1 = 0.0f;
        if ((unsigned)hhh < IMG_H && (unsigned)ww < IMG_W) {
            const float* src = x + (size_t)hchan * HW + hhh * IMG_W + ww;
            v0 = src[0];
            v1 = src[HW];                      // c+1: adjacent channel
        }
        tile2[(hdy * TC + xx) * TS2 + cp] = __floats2half2_rn(v0, v1);
    }
    __syncthreads();

    // ---- conv 5x5: accum rp2c/ra2c index = o*2 + cpair; half2 = (c,c+1) ----
    __half2 rp2c[8], ra2c[8];
    const __half2 z2 = __float2half2_rn(0.0f);
    #pragma unroll
    for (int i = 0; i < 8; ++i) { rp2c[i] = z2; ra2c[i] = z2; }

    const uint4* wq = (const uint4*)wpk2 + (t >> 1) * 50;  // wave-uniform base
    #pragma unroll
    for (int dy = 0; dy < 5; ++dy) {
        #pragma unroll
        for (int dx = 0; dx < 5; ++dx) {
            const __half2* t2 =
                &tile2[((rr + dy) * TC + px + dx) * TS2 + (q << 3)];
            union { uint4 u; __half2 hh[4]; } A, B, Wp_, Wa_;
            A.u   = *(const uint4*)t2;         // o0c01, o0c23, o1c01, o1c23
            B.u   = *(const uint4*)(t2 + 4);   // o2..o3
            Wp_.u = wq[(dy * 5 + dx) * 2];     // dup'd pos weights per o
            Wa_.u = wq[(dy * 5 + dx) * 2 + 1]; // dup'd app weights per o
            rp2c[0] = __hfma2(A.hh[0], Wp_.hh[0], rp2c[0]);  // o0 c01
            rp2c[1] = __hfma2(A.hh[1], Wp_.hh[0], rp2c[1]);  // o0 c23
            rp2c[2] = __hfma2(A.hh[2], Wp_.hh[1], rp2c[2]);  // o1
            rp2c[3] = __hfma2(A.hh[3], Wp_.hh[1], rp2c[3]);
            rp2c[4] = __hfma2(B.hh[0], Wp_.hh[2], rp2c[4]);  // o2
            rp2c[5] = __hfma2(B.hh[1], Wp_.hh[2], rp2c[5]);
            rp2c[6] = __hfma2(B.hh[2], Wp_.hh[3], rp2c[6]);  // o3
            rp2c[7] = __hfma2(B.hh[3], Wp_.hh[3], rp2c[7]);
            ra2c[0] = __hfma2(A.hh[0], Wa_.hh[0], ra2c[0]);  // app
            ra2c[1] = __hfma2(A.hh[1], Wa_.hh[0], ra2c[1]);
            ra2c[2] = __hfma2(A.hh[2], Wa_.hh[1], ra2c[2]);
            ra2c[3] = __hfma2(A.hh[3], Wa_.hh[1], ra2c[3]);
            ra2c[4] = __hfma2(B.hh[0], Wa_.hh[2], ra2c[4]);
            ra2c[5] = __hfma2(B.hh[1], Wa_.hh[2], ra2c[5]);
            ra2c[6] = __hfma2(B.hh[2], Wa_.hh[3], ra2c[6]);
            ra2c[7] = __hfma2(B.hh[3], Wa_.hh[3], ra2c[7]);
        }
    }

    // ---- emit u_hat[o][8] via v_dot2_f32_f16 (fp32 accumulate) ----
    float uh[4][8];
    {
        const float cx = (float)w * (1.0f / 96.0f);
        const float cy = (float)h * (1.0f / 96.0f);
        #pragma unroll
        for (int o = 0; o < 4; ++o) {
            const __half2* mp = &mposh[(o * 8 + t) * 8];   // wave-uniform
            __half2 r01 = rp2c[o * 2], r23 = rp2c[o * 2 + 1];
            #pragma unroll
            for (int c = 0; c < 4; ++c)
                uh[o][c] = fdot2h(r01, mp[c], fdot2h(r23, mp[4 + c], 0.0f));
            float r3f = __high2float(r23);     // p1=3 row (coord add target)
            uh[o][0] = fmaf(r3f, cx, uh[o][0]);
            uh[o][1] = fmaf(r3f, cy, uh[o][1]);

            const __half2* ma = &mapph[(o * 8 + t) * 8];
            const float*   cs = &acs[(o * 8 + t) * 4];
            __half2 s01 = ra2c[o * 2], s23 = ra2c[o * 2 + 1];
            const float bias = Ba[o * 8 + t];
            #pragma unroll
            for (int c = 0; c < 4; ++c)
                uh[o][4 + c] = fmaf(bias, cs[c],
                    fdot2h(s01, ma[c], fdot2h(s23, ma[4 + c], 0.0f)));
        }
    }

    route_store(uh, q, n * 8 + t, h * IMG_W + w, out);
}

extern "C" void kernel_launch(void* const* d_in, const int* in_sizes, int n_in,
                              void* d_out, int out_size, void* d_ws, size_t ws_size,
                              hipStream_t stream) {
    const float* x  = (const float*)d_in[0];
    const float* Wc = (const float*)d_in[1];
    const float* Wp = (const float*)d_in[2];
    const float* Wa = (const float*)d_in[3];
    const float* Ba = (const float*)d_in[4];
    float* outp = (float*)d_out;

    caps_one_kernel<<<dim3(IMG_W / TW, IMG_H / TH, 8), 1024, 0, stream>>>(
        x, Wc, Wp, Wa, Ba, outp);
}

// Round 14
// 118.586 us; speedup vs baseline: 1.0866x; 1.0692x over previous
//
#include <hip/hip_runtime.h>
#include <hip/hip_fp16.h>
#include <math.h>

#define IMG_H 96
#define IMG_W 96
#define HW (IMG_H * IMG_W)
#define TW 16          // output w-tile per block
#define TH 4           // output h-rows per block (split across waves)
#define TR (TH + 4)    // staged rows (halo 2 top + 2 bottom)
#define TC 20          // tile cols = TW + 4 halo
#define TS2 36         // half2 stride per x-column: 32 chan-pairs + 4 pad (2-way = free)

// fast 1-ULP hardware approximations (v_rcp_f32 / v_rsq_f32)
__device__ __forceinline__ float frcp(float x) { return __builtin_amdgcn_rcpf(x); }
__device__ __forceinline__ float frsq(float x) { return __builtin_amdgcn_rsqf(x); }

// quad (lanes tid&3) butterfly reductions via DPP quad_perm
__device__ __forceinline__ float quad_sum(float v) {
    v += __int_as_float(__builtin_amdgcn_update_dpp(
            0, __float_as_int(v), 0xB1, 0xF, 0xF, true));   // quad_perm [1,0,3,2]
    v += __int_as_float(__builtin_amdgcn_update_dpp(
            0, __float_as_int(v), 0x4E, 0xF, 0xF, true));   // quad_perm [2,3,0,1]
    return v;
}
__device__ __forceinline__ float quad_max(float v) {
    v = fmaxf(v, __int_as_float(__builtin_amdgcn_update_dpp(
            0, __float_as_int(v), 0xB1, 0xF, 0xF, true)));
    v = fmaxf(v, __int_as_float(__builtin_amdgcn_update_dpp(
            0, __float_as_int(v), 0x4E, 0xF, 0xF, true)));
    return v;
}

// 3-iter dynamic routing; quad lane q owns z rows: pos z = q*4+0..3,
// app z = 16+q*4+0..3. p_z lane-local; mx/n2/dp/da via quad butterflies.
// All divisions/sqrts use v_rcp_f32/v_rsq_f32 (1-ULP) -- the IEEE div
// sequences (~10 dependent ops each, 18 divisions total) were the longest
// serial chain in the kernel.
__device__ __forceinline__ void route_store(const float (*uh)[8], int q, int nt,
                                            int pix, float* __restrict__ out)
{
    float bb[4] = {0.0f, 0.0f, 0.0f, 0.0f};
    #pragma unroll
    for (int it = 0; it < 2; ++it) {
        float r0 = frcp(1.0f + __expf(-bb[0]));
        float r1 = frcp(1.0f + __expf(-bb[1]));
        float r2 = frcp(1.0f + __expf(-bb[2]));
        float r3 = frcp(1.0f + __expf(-bb[3]));
        float pz[4], pa[4];
        #pragma unroll
        for (int j = 0; j < 4; ++j)
            pz[j] = fmaf(uh[0][j], r0, fmaf(uh[1][j], r1,
                    fmaf(uh[2][j], r2, uh[3][j] * r3)));
        float mx = quad_max(fmaxf(fmaxf(fabsf(pz[0]), fabsf(pz[1])),
                                  fmaxf(fabsf(pz[2]), fabsf(pz[3]))));
        float dp[4];
        #pragma unroll
        for (int o = 0; o < 4; ++o)
            dp[o] = quad_sum(fmaf(uh[o][0], pz[0], fmaf(uh[o][1], pz[1],
                             fmaf(uh[o][2], pz[2], uh[o][3] * pz[3]))));
        #pragma unroll
        for (int j = 0; j < 4; ++j)
            pa[j] = fmaf(uh[0][4 + j], r0, fmaf(uh[1][4 + j], r1,
                    fmaf(uh[2][4 + j], r2, uh[3][4 + j] * r3)));
        float n2 = quad_sum(fmaf(pa[0], pa[0], fmaf(pa[1], pa[1],
                            fmaf(pa[2], pa[2], pa[3] * pa[3]))));
        float invm = frcp(mx);                                // psquash
        float sc   = n2 * frcp(1.0f + n2) * frsq(n2 + 1e-9f); // matwo squash
        #pragma unroll
        for (int o = 0; o < 4; ++o) {
            float da = quad_sum(fmaf(uh[o][4], pa[0], fmaf(uh[o][5], pa[1],
                               fmaf(uh[o][6], pa[2], uh[o][7] * pa[3]))));
            bb[o] += (invm * dp[o]) * (sc * da);
        }
    }
    float r0 = frcp(1.0f + __expf(-bb[0]));
    float r1 = frcp(1.0f + __expf(-bb[1]));
    float r2 = frcp(1.0f + __expf(-bb[2]));
    float r3 = frcp(1.0f + __expf(-bb[3]));
    float pz[4], pa[4];
    #pragma unroll
    for (int j = 0; j < 4; ++j)
        pz[j] = fmaf(uh[0][j], r0, fmaf(uh[1][j], r1,
                fmaf(uh[2][j], r2, uh[3][j] * r3)));
    float mx = quad_max(fmaxf(fmaxf(fabsf(pz[0]), fabsf(pz[1])),
                              fmaxf(fabsf(pz[2]), fabsf(pz[3]))));
    #pragma unroll
    for (int j = 0; j < 4; ++j)
        pa[j] = fmaf(uh[0][4 + j], r0, fmaf(uh[1][4 + j], r1,
                fmaf(uh[2][4 + j], r2, uh[3][4 + j] * r3)));
    float n2 = quad_sum(fmaf(pa[0], pa[0], fmaf(pa[1], pa[1],
                        fmaf(pa[2], pa[2], pa[3] * pa[3]))));
    float invm = frcp(mx);
    float sc   = n2 * frcp(1.0f + n2) * frsq(n2 + 1e-9f);
    // unmasked stores: lane q owns z = q*4+j (pos) and 16+q*4+j (app)
    float* op = out + ((size_t)nt * 32 + (q << 2)) * HW + pix;
    op[0 * HW] = pz[0] * invm;
    op[1 * HW] = pz[1] * invm;
    op[2 * HW] = pz[2] * invm;
    op[3 * HW] = pz[3] * invm;
    op[16 * HW] = pa[0] * sc;
    op[17 * HW] = pa[1] * sc;
    op[18 * HW] = pa[2] * sc;
    op[19 * HW] = pa[3] * sc;
}

// Block 1024 = 4 q (lane&3) x 16 px x 16 waves; wave wv handles
// capsule t = parity + 2*(wv&3) and output row rr = wv>>2 (0..3).
// Grid (6, 24, n*2+parity); block stages an 8-row tile serving 4 output rows.
// Staging is EXACT at 1024 threads: interior 1 unit/thread, halo 1 unit/thread.
// LDS channel slot s = zq*16 + c*4 + o  ->  input chan = o*32 + parity*16 + zq*4 + c
// __launch_bounds__(1024, 8): pin VGPR <= 64 so 2 blocks (32 waves) stay resident.
__global__ void __launch_bounds__(1024, 8)
caps_one_kernel(const float* __restrict__ x,    // (4,4,32,96,96)
                const float* __restrict__ Wc,   // (4,5,5,1,8)
                const float* __restrict__ Wp,   // (4,16,8)
                const float* __restrict__ Wa,   // (4,16,8)
                const float* __restrict__ Ba,   // (4,8)
                float* __restrict__ out)        // (4,8,32,96,96)
{
    __shared__ __align__(16) __half2 tile2[TR * TC * TS2];  // 23.0 KB
    __shared__ __align__(16) __half2 wpk[400];  // [fp][tap][g]: g = pos(o01),pos(o23),app(o01),app(o23)
    __shared__ __align__(16) float   msh[512];  // (o*8+t)*16 normalized W_pos
    __shared__ __align__(16) float   ash[512];  // (o*8+t)*16 raw W_app

    const int tid    = threadIdx.x;
    const int q      = tid & 3;                // z-row quad lane
    const int px     = (tid >> 2) & 15;
    const int wv     = tid >> 6;               // wave 0..15
    const int rr     = wv >> 2;                // output row within tile (0..3)
    const int wb     = blockIdx.x * TW;
    const int h0     = blockIdx.y * TH;
    const int n      = blockIdx.z >> 1;
    const int parity = blockIdx.z & 1;
    const int t      = parity + 2 * (wv & 3);  // capsule type for this wave
    const int w      = wb + px;
    const int h      = h0 + rr;

    // ---- precompute: packed conv weights, o-paired ----
    if (tid < 400) {
        int i   = tid;
        int fp  = i / 100;
        int rem = i - fp * 100;
        int tap = rem >> 2;
        int g   = i & 3;
        int oe  = (g & 1) << 1;                // 0 or 2
        int f   = fp + ((g >> 1) << 2);        // pos: fp, app: fp+4
        wpk[i] = __floats2half2_rn(Wc[oe * 200 + tap * 8 + f],
                                   Wc[(oe + 1) * 200 + tap * 8 + f]);
    }
    // ---- precompute: normalized pos matrices + raw app matrices ----
    if (tid >= 512 && tid < 640) {
        int j  = tid - 512;
        int c  = j & 3;                        // p1 column
        int tt = (j >> 2) & 7;
        int oo = j >> 5;
        const float* src = Wp + oo * 128 + tt * 16 + c;
        float v0 = src[0], v1 = src[4], v2 = src[8], v3 = src[12];
        float s = v0 * v0 + v1 * v1 + v2 * v2 + v3 * v3;
        float inv = 1.0f / sqrtf(fmaxf(s, 1e-12f));
        float* dst = msh + (oo * 8 + tt) * 16 + c;
        dst[0] = v0 * inv; dst[4] = v1 * inv; dst[8] = v2 * inv; dst[12] = v3 * inv;
    } else if (tid >= 640 && tid < 768) {
        int i = tid - 640;
        ((float4*)ash)[i] = ((const float4*)Wa)[i];
    }
    // ---- staging: interior, EXACT one b128 unit per thread ----
    {
        const int col = tid & 15;
        const int g   = tid >> 4;              // 0..63 = dy*8 + cpg exact
        const int dy    = g >> 3;              // 0..7
        const int cpg   = g & 7;
        const int hh    = h0 + dy - 2;
        const int zq    = cpg >> 1;
        const int cbase = (cpg & 1) << 1;
        const int chan  = n * 128 + parity * 16 + zq * 4 + cbase;  // o=0 comp
        float v[8];
        #pragma unroll
        for (int j = 0; j < 8; ++j) v[j] = 0.0f;
        if ((unsigned)hh < IMG_H) {
            const float* src = x + (size_t)chan * HW + hh * IMG_W + wb + col;
            #pragma unroll
            for (int j = 0; j < 8; ++j)           // o = j&3, c = cbase+(j>>2)
                v[j] = src[(size_t)((j & 3) * 32 + (j >> 2)) * HW];
        }
        __half2 h4[4];
        #pragma unroll
        for (int j = 0; j < 4; ++j)               // pairs (o even, o odd)
            h4[j] = __floats2half2_rn(v[2 * j], v[2 * j + 1]);
        *(uint4*)&tile2[(dy * TC + 2 + col) * TS2 + (cpg << 2)] =
            *(const uint4*)h4;

        // halo: x in {0,1,18,19}, EXACT one half2 unit per thread
        const int m  = tid & 3;
        const int xx = (m < 2) ? m : (m + TW);
        const int ww = wb - 2 + xx;
        const int rh = tid >> 2;               // 0..255 = dy*32 + cp exact
        const int hdy = rh >> 5;               // 0..7
        const int cp  = rh & 31;
        const int hhh = h0 + hdy - 2;
        const int o0  = (cp & 1) << 1;
        const int hc  = (cp >> 1) & 3;
        const int hzq = cp >> 3;
        const int hchan = n * 128 + o0 * 32 + parity * 16 + hzq * 4 + hc;
        float v0 = 0.0f, v1 = 0.0f;
        if ((unsigned)hhh < IMG_H && (unsigned)ww < IMG_W) {
            const float* src = x + (size_t)hchan * HW + hhh * IMG_W + ww;
            v0 = src[0];
            v1 = src[(size_t)32 * HW];
        }
        tile2[(hdy * TC + xx) * TS2 + cp] = __floats2half2_rn(v0, v1);
    }
    __syncthreads();

    // ---- conv 5x5: lane q computes c=0..3 for ALL 4 types o, packed fp16 ----
    __half2 rp2[8], ra2[8];
    const __half2 z2 = __float2half2_rn(0.0f);
    #pragma unroll
    for (int i = 0; i < 8; ++i) { rp2[i] = z2; ra2[i] = z2; }

    const uint4* wb4 = (const uint4*)&wpk[(t >> 1) * 100];  // wave-uniform base
    #pragma unroll
    for (int dy = 0; dy < 5; ++dy) {
        #pragma unroll
        for (int dx = 0; dx < 5; ++dx) {
            const __half2* t2 =
                &tile2[((rr + dy) * TC + px + dx) * TS2 + (q << 3)];
            union { uint4 u; __half2 hh[4]; } A, B, Wt;
            A.u  = *(const uint4*)t2;
            B.u  = *(const uint4*)(t2 + 4);
            Wt.u = wb4[dy * 5 + dx];           // broadcast read
            rp2[0] = __hfma2(A.hh[0], Wt.hh[0], rp2[0]);  // c0 o01 pos
            rp2[1] = __hfma2(A.hh[1], Wt.hh[1], rp2[1]);  // c0 o23 pos
            rp2[2] = __hfma2(A.hh[2], Wt.hh[0], rp2[2]);  // c1 o01
            rp2[3] = __hfma2(A.hh[3], Wt.hh[1], rp2[3]);  // c1 o23
            rp2[4] = __hfma2(B.hh[0], Wt.hh[0], rp2[4]);  // c2 o01
            rp2[5] = __hfma2(B.hh[1], Wt.hh[1], rp2[5]);  // c2 o23
            rp2[6] = __hfma2(B.hh[2], Wt.hh[0], rp2[6]);  // c3 o01
            rp2[7] = __hfma2(B.hh[3], Wt.hh[1], rp2[7]);  // c3 o23
            ra2[0] = __hfma2(A.hh[0], Wt.hh[2], ra2[0]);  // app
            ra2[1] = __hfma2(A.hh[1], Wt.hh[3], ra2[1]);
            ra2[2] = __hfma2(A.hh[2], Wt.hh[2], ra2[2]);
            ra2[3] = __hfma2(A.hh[3], Wt.hh[3], ra2[3]);
            ra2[4] = __hfma2(B.hh[0], Wt.hh[2], ra2[4]);
            ra2[5] = __hfma2(B.hh[1], Wt.hh[3], ra2[5]);
            ra2[6] = __hfma2(B.hh[2], Wt.hh[2], ra2[6]);
            ra2[7] = __hfma2(B.hh[3], Wt.hh[3], ra2[7]);
        }
    }

    // ---- emit u_hat[o][8]: per-type matrices (pos normalized + coord; app raw + bias)
    float uh[4][8];
    {
        const float cx = (float)w * (1.0f / 96.0f);
        const float cy = (float)h * (1.0f / 96.0f);
        #pragma unroll
        for (int o = 0; o < 4; ++o) {
            const float* mb = &msh[(o * 8 + t) * 16];    // wave-uniform addr
            float4 m0 = *(const float4*)(mb + 0);
            float4 m1 = *(const float4*)(mb + 4);
            float4 m2 = *(const float4*)(mb + 8);
            float4 m3 = *(const float4*)(mb + 12);
            m3.x += cx;                         // coord add [row3,col0]
            m3.y += cy;                         // [row3,col1]
            const int pr = o >> 1;
            float r0, r1, r2, r3;
            if (o & 1) {
                r0 = __high2float(rp2[0 + pr]); r1 = __high2float(rp2[2 + pr]);
                r2 = __high2float(rp2[4 + pr]); r3 = __high2float(rp2[6 + pr]);
            } else {
                r0 = __low2float(rp2[0 + pr]);  r1 = __low2float(rp2[2 + pr]);
                r2 = __low2float(rp2[4 + pr]);  r3 = __low2float(rp2[6 + pr]);
            }
            uh[o][0] = r0 * m0.x + r1 * m1.x + r2 * m2.x + r3 * m3.x;
            uh[o][1] = r0 * m0.y + r1 * m1.y + r2 * m2.y + r3 * m3.y;
            uh[o][2] = r0 * m0.z + r1 * m1.z + r2 * m2.z + r3 * m3.z;
            uh[o][3] = r0 * m0.w + r1 * m1.w + r2 * m2.w + r3 * m3.w;
        }
        #pragma unroll
        for (int o = 0; o < 4; ++o) {
            const float* ab = &ash[(o * 8 + t) * 16];
            float4 a0 = *(const float4*)(ab + 0);
            float4 a1 = *(const float4*)(ab + 4);
            float4 a2 = *(const float4*)(ab + 8);
            float4 a3 = *(const float4*)(ab + 12);
            const float bias = Ba[o * 8 + t];
            const int pr = o >> 1;
            float r0, r1, r2, r3;
            if (o & 1) {
                r0 = __high2float(ra2[0 + pr]); r1 = __high2float(ra2[2 + pr]);
                r2 = __high2float(ra2[4 + pr]); r3 = __high2float(ra2[6 + pr]);
            } else {
                r0 = __low2float(ra2[0 + pr]);  r1 = __low2float(ra2[2 + pr]);
                r2 = __low2float(ra2[4 + pr]);  r3 = __low2float(ra2[6 + pr]);
            }
            r0 += bias; r1 += bias; r2 += bias; r3 += bias;
            uh[o][4] = r0 * a0.x + r1 * a1.x + r2 * a2.x + r3 * a3.x;
            uh[o][5] = r0 * a0.y + r1 * a1.y + r2 * a2.y + r3 * a3.y;
            uh[o][6] = r0 * a0.z + r1 * a1.z + r2 * a2.z + r3 * a3.z;
            uh[o][7] = r0 * a0.w + r1 * a1.w + r2 * a2.w + r3 * a3.w;
        }
    }

    route_store(uh, q, n * 8 + t, h * IMG_W + w, out);
}

extern "C" void kernel_launch(void* const* d_in, const int* in_sizes, int n_in,
                              void* d_out, int out_size, void* d_ws, size_t ws_size,
                              hipStream_t stream) {
    const float* x  = (const float*)d_in[0];
    const float* Wc = (const float*)d_in[1];
    const float* Wp = (const float*)d_in[2];
    const float* Wa = (const float*)d_in[3];
    const float* Ba = (const float*)d_in[4];
    float* outp = (float*)d_out;

    caps_one_kernel<<<dim3(IMG_W / TW, IMG_H / TH, 8), 1024, 0, stream>>>(
        x, Wc, Wp, Wa, Ba, outp);
}